// Round 1
// 88.088 us; speedup vs baseline: 1.0014x; 1.0014x over previous
//
#include <hip/hip_runtime.h>
#include <math.h>

// N=50000 atoms, 8 types, dim_q = num_neurons = 64.
//
// WORKSPACE-FREE variant. Theory: the 88 us measurement is dominated by the
// harness's 256 MiB workspace poison fills (44-45 us each at ~74% HBM peak in
// rocprof), not by our ~10 us of kernel work. This version never touches d_ws:
// no bucketing, no sorted[] buffer, no fill[] counters. Instead ALL 8 types'
// weights live in LDS simultaneously (131 KB of the 160 KB/CU) and each thread
// runs its own atom's 64x64 matvec with per-atom type, reading weights from LDS.
//
// Bank layout: per-type stride 4100 floats (4096+4). Type base % 32 banks
// = z*4, so the 8 types' float4 reads at the same (d,k) occupy 8 DISJOINT
// 4-bank spans -> conflict-free ds_read_b128 even with mixed types in a wave
// (same-type lanes broadcast from the same address).

#define NUM_TYPES 8
#define DIM 64
#define W_STRIDE 4100                                   // floats per type slab
#define LDS_FLOATS (NUM_TYPES * W_STRIDE + 2 * NUM_TYPES * DIM)
#define LDS_BYTES  (LDS_FLOATS * 4)                     // 135,296 B < 160 KiB

__global__ __launch_bounds__(256) void fused_mlp_kernel(
    const float* __restrict__ desc, const float* __restrict__ W0,
    const float* __restrict__ b0, const float* __restrict__ W1,
    const float* __restrict__ b1, const int* __restrict__ Z,
    float* __restrict__ out, int N)
{
    extern __shared__ float lds[];
    float* W0s = lds;                                   // [8][64][64], stride 4100/type
    float* b0s = lds + NUM_TYPES * W_STRIDE;            // [8][64]
    float* W1s = b0s + NUM_TYPES * DIM;                 // [8][64]
    __shared__ float wsum[4];

    const int tid = threadIdx.x;

    // ---- stage weights: W0 = 8 x 1024 float4, b0/W1 = 512 floats each ----
    #pragma unroll
    for (int t = 0; t < NUM_TYPES; ++t) {
        float4* dst = (float4*)(W0s + t * W_STRIDE);    // 4100 % 4 == 0: aligned
        const float4* src = (const float4*)(W0 + t * DIM * DIM);
        #pragma unroll
        for (int it = 0; it < 4; ++it)
            dst[tid + it * 256] = src[tid + it * 256];
    }
    b0s[tid]       = b0[tid];
    b0s[tid + 256] = b0[tid + 256];
    W1s[tid]       = W1[tid];
    W1s[tid + 256] = W1[tid + 256];
    __syncthreads();

    // ---- per-thread matvec: h = q @ W0[z] + b0[z]; e = sum(tanh(h) * W1[z]) ----
    const int i = blockIdx.x * 256 + tid;
    float e = 0.0f;
    if (i < N) {
        const int z = Z[i];
        const float4* Wz  = (const float4*)(W0s + z * W_STRIDE);
        const float4* qv  = (const float4*)(desc + (size_t)i * DIM);
        const float4* bz  = (const float4*)(b0s + z * DIM);
        const float4* w1z = (const float4*)(W1s + z * DIM);

        float4 h[16];
        #pragma unroll
        for (int kq = 0; kq < 16; ++kq) h[kq] = bz[kq];

        #pragma unroll 4
        for (int d4 = 0; d4 < 16; ++d4) {
            float4 q4 = qv[d4];                          // 16B global, L1-friendly
            #pragma unroll
            for (int dd = 0; dd < 4; ++dd) {
                float qd = (dd == 0) ? q4.x : (dd == 1) ? q4.y
                         : (dd == 2) ? q4.z : q4.w;      // resolved at compile time
                const float4* Wrow = Wz + (d4 * 4 + dd) * 16;
                #pragma unroll
                for (int kq = 0; kq < 16; ++kq) {
                    float4 w = Wrow[kq];                 // conflict-free b128
                    h[kq].x = fmaf(qd, w.x, h[kq].x);
                    h[kq].y = fmaf(qd, w.y, h[kq].y);
                    h[kq].z = fmaf(qd, w.z, h[kq].z);
                    h[kq].w = fmaf(qd, w.w, h[kq].w);
                }
            }
        }

        // epilogue: fast tanh (validated absmax 0.0 in prior rounds) + dot W1
        #pragma unroll
        for (int kq = 0; kq < 16; ++kq) {
            float4 w1 = w1z[kq];
            float hv[4] = {h[kq].x, h[kq].y, h[kq].z, h[kq].w};
            float wv[4] = {w1.x, w1.y, w1.z, w1.w};
            #pragma unroll
            for (int j = 0; j < 4; ++j) {
                float u  = __expf(2.0f * hv[j]);                  // e^{2x}
                float th = 1.0f - __fdividef(2.0f, u + 1.0f);     // tanh(x)
                e = fmaf(th, wv[j], e);
            }
        }
    }

    // global bias term: reference adds b1 per atom -> + N*b1 total (N < 2^24, exact)
    if (blockIdx.x == 0 && tid == 0) e += (float)N * b1[0];

    // wave(64) shuffle reduce -> cross-wave LDS -> one atomicAdd per block
    #pragma unroll
    for (int o = 32; o > 0; o >>= 1) e += __shfl_down(e, o, 64);
    if ((tid & 63) == 0) wsum[tid >> 6] = e;
    __syncthreads();
    if (tid == 0) atomicAdd(out, wsum[0] + wsum[1] + wsum[2] + wsum[3]);
}

// ---------------------------------------------------------------------------
extern "C" void kernel_launch(void* const* d_in, const int* in_sizes, int n_in,
                              void* d_out, int out_size, void* d_ws, size_t ws_size,
                              hipStream_t stream)
{
    const float* desc = (const float*)d_in[0];
    const float* W0   = (const float*)d_in[1];
    const float* b0   = (const float*)d_in[2];
    const float* W1   = (const float*)d_in[3];
    const float* b1   = (const float*)d_in[4];
    const int*   Z    = (const int*)d_in[5];
    const int N = in_sizes[5];

    // 135 KB dynamic LDS: opt in once (ROCm may allow it regardless; harmless).
    static bool attr_done = false;
    if (!attr_done) {
        (void)hipFuncSetAttribute((const void*)fused_mlp_kernel,
                                  hipFuncAttributeMaxDynamicSharedMemorySize,
                                  LDS_BYTES);
        attr_done = true;
    }

    // d_ws deliberately untouched: testing whether the 256 MiB workspace poison
    // fill (44-45 us per iteration in rocprof) is conditional on workspace use.
    hipMemsetAsync(d_out, 0, sizeof(float), stream);   // clears 0xAA poison

    fused_mlp_kernel<<<(N + 255) / 256, 256, LDS_BYTES, stream>>>(
        desc, W0, b0, W1, b1, Z, (float*)d_out, N);
}